// Round 1
// baseline (5563.893 us; speedup 1.0000x reference)
//
#include <hip/hip_runtime.h>
#include <hip/hip_bf16.h>
#include <stdint.h>

// Problem dims
#define T_HRZ 1024
#define NBAT  128
#define NHID  256
#define NPAIR 128
#define NUIN  64
#define NYOUT 64
#define LCH   16   // chunk length
#define CCH   64   // number of chunks

// Workspace layout (float offsets). ~8.6 MB total.
#define WS_LAM   0         // lr[128], li[128]
#define WS_LAML  256       // lambda^16 r[128], i[128]
#define WS_X0P   512       // x0 pair-interleaved [b][j][2] : 128*128*2
#define WS_WBU   33280     // bf16 B-frags for Bu GEMM [nt16][kk2][lane64][j8]
#define WS_WBY   41472     // bf16 B-frags for Y GEMM  [nt4][kk8][lane64][j8]
#define WS_EPUB  49664     // u64 entry-state publications [c][b][j] (2,097,152 float slots)
#define WS_FLAG  2146816   // u32 flag[c][b] (8192) + ticket u32 at [CCH*NBAT]

// X16 LDS tile: packed bf16 pairs, pitch 264 shorts (132 dwords, 132%32=4)
#define X16_PITCH 264
// XA LDS tile: padded A-frag layout, b-stride 136 shorts, kk-stride 552
#define XA_SB 136
#define XA_SK 552

typedef __attribute__((ext_vector_type(8))) short short8;
typedef __attribute__((ext_vector_type(4))) float float4v;

union Frag { short8 s8; unsigned int u32[4]; };

__device__ __forceinline__ unsigned int f2bf_bits(float x) {
  unsigned int u = __float_as_uint(x);
  return (u + 0x7fffu + ((u >> 16) & 1u)) >> 16;  // RNE
}

__device__ __forceinline__ unsigned int pkbf(float a, float b) {
  __hip_bfloat162 h = __float22bfloat162_rn(make_float2(a, b));
  union { __hip_bfloat162 h2; unsigned int u; } cv; cv.h2 = h; return cv.u;
}

// ---------------------------------------------------------------------------
// K1: prep. grid (NBAT+3) x 256. Also zeroes chain flags + ticket each launch.
// ---------------------------------------------------------------------------
__global__ __launch_bounds__(256) void k_prep(
    const float* __restrict__ y0, const float* __restrict__ lrc,
    const float* __restrict__ lic, const float* __restrict__ Bm,
    const float* __restrict__ Wy2x, const float* __restrict__ by2x,
    const float* __restrict__ Wx2y, float* __restrict__ ws)
{
  int blk = blockIdx.x;
  int h = threadIdx.x;  // 0..255
  if (blk < NBAT) {
    __shared__ float y0s[NYOUT];
    if (h < NYOUT) y0s[h] = y0[blk * NYOUT + h];
    __syncthreads();
    float acc = by2x[h];
    const float* wr = Wy2x + h * NYOUT;
#pragma unroll 16
    for (int k = 0; k < NYOUT; ++k) acc += y0s[k] * wr[k];
    int j = h & (NPAIR - 1);
    int comp = h >> 7;
    ws[WS_X0P + (blk * NPAIR + j) * 2 + comp] = acc;
  } else if (blk == NBAT) {
    // zero chain flags + ticket counter (must happen before k_main each launch)
    unsigned int* fl = (unsigned int*)(ws + WS_FLAG);
    for (int i = h; i < CCH * NBAT + 1; i += 256) fl[i] = 0u;
    if (h < NPAIR) {
      float a  = fabsf(lrc[h]);
      float r  = expf(-a);
      float th = 1.5707963267948966f * lic[h];
      float lr = r * cosf(th);
      float li = r * sinf(th);
      ws[WS_LAM + h]         = lr;
      ws[WS_LAM + NPAIR + h] = li;
      float pr = lr, pi_ = li;
      for (int l = 1; l < LCH; ++l) {
        float nr = pr * lr - pi_ * li;
        float ni = pr * li + pi_ * lr;
        pr = nr; pi_ = ni;
      }
      ws[WS_LAML + h]         = pr;  // lambda^16
      ws[WS_LAML + NPAIR + h] = pi_;
    }
  } else if (blk == NBAT + 1) {
    unsigned short* wbu = (unsigned short*)(ws + WS_WBU);
    for (int idx = h; idx < 16384; idx += 256) {
      int nt   = idx >> 10;
      int kk   = (idx >> 9) & 1;
      int lane = (idx >> 3) & 63;
      int jj   = idx & 7;
      int u  = kk * 32 + (lane >> 4) * 8 + jj;
      int hh = nt * 16 + (lane & 15);
      float a2 = fabsf(lrc[hh & (NPAIR - 1)]);
      float nf = sqrtf(1.f - expf(-2.f * a2));
      wbu[idx] = (unsigned short)f2bf_bits(Bm[hh * NUIN + u] * nf);
    }
  } else {
    unsigned short* wby = (unsigned short*)(ws + WS_WBY);
    for (int idx = h; idx < 16384; idx += 256) {
      int nt   = idx >> 12;
      int kk   = (idx >> 9) & 7;
      int lane = (idx >> 3) & 63;
      int jj   = idx & 7;
      int hh = kk * 32 + (lane >> 4) * 8 + jj;
      int y  = nt * 16 + (lane & 15);
      wby[idx] = (unsigned short)f2bf_bits(Wx2y[y * NHID + hh]);
    }
  }
}

// ---------------------------------------------------------------------------
// K2: fused single-pass chained scan. grid CCH*NBAT x 128 (2 waves).
// Ticket -> (c,b). Local Bu tile via MFMA -> LDS transpose -> chunk sum,
// decoupled-lookback chain over c (per-b), then finish scan + Y-MFMA + store.
// U is read ONCE; pk[] stays in registers between sum and finish passes.
// ---------------------------------------------------------------------------
__global__ __launch_bounds__(128, 4) void k_main(
    const float* __restrict__ U, const float* __restrict__ bx2y,
    float* __restrict__ out, float* __restrict__ ws)
{
  // X16 (16*264 = 4224 shorts) and XA (8*552 = 4416 shorts) aliased: XA is
  // only written after the phase-2 __syncthreads, all X16 reads precede it.
  __shared__ unsigned short SM[8 * XA_SK];
  __shared__ unsigned int vid_s;
  int tid = threadIdx.x, wave = tid >> 6, lane = tid & 63;
  int l15 = lane & 15, q = lane >> 4;

  unsigned int* flags = (unsigned int*)(ws + WS_FLAG);
  if (tid == 0) vid_s = atomicAdd(flags + CCH * NBAT, 1u);  // ticket = start order
  __syncthreads();
  unsigned int vid = vid_s;
  int c = (int)(vid >> 7);        // chunk row (chain dimension)
  int b = (int)(vid & (NBAT - 1));

  // ---- phase 1: Bu tile for chunk c ----
  const float* urow = U + ((size_t)(c * LCH + l15) * NBAT + b) * NUIN;
  Frag afr[2];
#pragma unroll
  for (int kk = 0; kk < 2; ++kk) {
    int u0 = kk * 32 + q * 8;
    float4 va = *(const float4*)(urow + u0);
    float4 vb = *(const float4*)(urow + u0 + 4);
    afr[kk].u32[0] = pkbf(va.x, va.y);
    afr[kk].u32[1] = pkbf(va.z, va.w);
    afr[kk].u32[2] = pkbf(vb.x, vb.y);
    afr[kk].u32[3] = pkbf(vb.z, vb.w);
  }

  int j = tid;
  float lr = ws[WS_LAM + j],  li = ws[WS_LAM + NPAIR + j];
  float Lr = ws[WS_LAML + j], Li = ws[WS_LAML + NPAIR + j];

  const short8* wbu = (const short8*)(ws + WS_WBU);
  float4v z = {0.f, 0.f, 0.f, 0.f};
  float4v acc[8];
#pragma unroll
  for (int n = 0; n < 8; ++n) acc[n] = z;
#pragma unroll
  for (int n = 0; n < 8; ++n) {
    int nt = wave * 8 + n;
    acc[n] = __builtin_amdgcn_mfma_f32_16x16x32_bf16(afr[0].s8, wbu[(nt * 2 + 0) * 64 + lane], acc[n], 0, 0, 0);
    acc[n] = __builtin_amdgcn_mfma_f32_16x16x32_bf16(afr[1].s8, wbu[(nt * 2 + 1) * 64 + lane], acc[n], 0, 0, 0);
  }

  // C-layout (t=q*4+r, h=(wave*8+n)*16+l15) -> packed pair LDS
#pragma unroll
  for (int n = 0; n < 8; ++n) {
    int hh = (wave * 8 + n) * 16 + l15;
    int off = (hh & 127) * 2 + (hh >> 7);
#pragma unroll
    for (int r = 0; r < 4; ++r)
      SM[(q * 4 + r) * X16_PITCH + off] = (unsigned short)f2bf_bits(acc[n][r]);
  }
  __syncthreads();

  // per-thread packed Bu column -> registers (reused by finish pass)
  unsigned int pk[LCH];
#pragma unroll
  for (int l = 0; l < LCH; ++l)
    pk[l] = *(const unsigned int*)(SM + l * X16_PITCH + j * 2);

  // chunk-local weighted sum s = sum_l lambda^(15-l) * bu_l
  float s1 = 0.f, s2 = 0.f;
#pragma unroll
  for (int l = 0; l < LCH; ++l) {
    float v1 = __uint_as_float(pk[l] << 16);
    float v2 = __uint_as_float(pk[l] & 0xffff0000u);
    float n1 = lr * s1 - li * s2 + v1;
    float n2 = li * s1 + lr * s2 + v2;
    s1 = n1; s2 = n2;
  }

  // ---- phase 2: chain (decoupled lookback, 1 link per chunk row) ----
  unsigned long long* epub = (unsigned long long*)(ws + WS_EPUB);
  const size_t cs = (size_t)NBAT * NPAIR;
  size_t o0 = (size_t)b * NPAIR + j;
  float e1, e2;
  if (c == 0) {
    e1 = ws[WS_X0P + (b * NPAIR + j) * 2 + 0];
    e2 = ws[WS_X0P + (b * NPAIR + j) * 2 + 1];
  } else {
    unsigned int* fp = flags + (c - 1) * NBAT + b;
    while (__hip_atomic_load(fp, __ATOMIC_ACQUIRE, __HIP_MEMORY_SCOPE_AGENT) == 0u)
      __builtin_amdgcn_s_sleep(1);
    unsigned long long pv = __hip_atomic_load(epub + (size_t)(c - 1) * cs + o0,
                                              __ATOMIC_RELAXED, __HIP_MEMORY_SCOPE_AGENT);
    e1 = __uint_as_float((unsigned int)pv);
    e2 = __uint_as_float((unsigned int)(pv >> 32));
  }
  if (c < CCH - 1) {
    float p1 = Lr * e1 - Li * e2 + s1;
    float p2 = Li * e1 + Lr * e2 + s2;
    unsigned long long pv = ((unsigned long long)__float_as_uint(p2) << 32)
                          |  (unsigned long long)__float_as_uint(p1);
    __hip_atomic_store(epub + (size_t)c * cs + o0, pv,
                       __ATOMIC_RELAXED, __HIP_MEMORY_SCOPE_AGENT);
  }
  // Orders all threads' epub stores before tid0's flag release; also fences
  // X16 reads (pk) against the XA writes below (aliased LDS).
  __syncthreads();
  if (tid == 0 && c < CCH - 1)
    __hip_atomic_store(flags + c * NBAT + b, 1u,
                       __ATOMIC_RELEASE, __HIP_MEMORY_SCOPE_AGENT);

  // ---- phase 3: finish scan from e, write bf16 X into padded XA LDS ----
  int base1 = (j >> 5) * XA_SK       + ((j >> 3) & 3) * XA_SB + (j & 7);
  int base2 = ((j >> 5) + 4) * XA_SK + ((j >> 3) & 3) * XA_SB + (j & 7);
  float x1 = e1, x2 = e2;
#pragma unroll
  for (int l = 0; l < LCH; ++l) {
    float v1 = __uint_as_float(pk[l] << 16);
    float v2 = __uint_as_float(pk[l] & 0xffff0000u);
    float n1 = lr * x1 - li * x2 + v1;
    float n2 = li * x1 + lr * x2 + v2;
    x1 = n1; x2 = n2;
    SM[base1 + l * 8] = (unsigned short)f2bf_bits(x1);
    SM[base2 + l * 8] = (unsigned short)f2bf_bits(x2);
  }
  __syncthreads();

  // ---- Y = X @ W_x2y^T via MFMA ----
  const short8* wby = (const short8*)(ws + WS_WBY);
  float4v acc0 = z, acc1 = z;
  int nt0 = wave * 2, nt1 = nt0 + 1;
#pragma unroll
  for (int kk = 0; kk < 8; ++kk) {
    short8 a = *(const short8*)(SM + kk * XA_SK + q * XA_SB + l15 * 8);
    acc0 = __builtin_amdgcn_mfma_f32_16x16x32_bf16(a, wby[(nt0 * 8 + kk) * 64 + lane], acc0, 0, 0, 0);
    acc1 = __builtin_amdgcn_mfma_f32_16x16x32_bf16(a, wby[(nt1 * 8 + kk) * 64 + lane], acc1, 0, 0, 0);
  }

  float bias0 = bx2y[nt0 * 16 + l15];
  float bias1 = bx2y[nt1 * 16 + l15];
#pragma unroll
  for (int r = 0; r < 4; ++r) {
    int row = q * 4 + r;  // t within chunk
    size_t o = ((size_t)(c * LCH + row) * NBAT + b) * NYOUT;
    out[o + nt0 * 16 + l15] = acc0[r] + bias0;
    out[o + nt1 * 16 + l15] = acc1[r] + bias1;
  }
}

// ---------------------------------------------------------------------------
extern "C" void kernel_launch(void* const* d_in, const int* in_sizes, int n_in,
                              void* d_out, int out_size, void* d_ws, size_t ws_size,
                              hipStream_t stream) {
  (void)in_sizes; (void)n_in; (void)out_size; (void)ws_size;
  const float* y0   = (const float*)d_in[0];
  const float* U    = (const float*)d_in[1];
  const float* lrc  = (const float*)d_in[2];
  const float* lic  = (const float*)d_in[3];
  const float* Bm   = (const float*)d_in[4];
  const float* Wy2x = (const float*)d_in[5];
  const float* by2x = (const float*)d_in[6];
  const float* Wx2y = (const float*)d_in[7];
  const float* bx2y = (const float*)d_in[8];
  float* out = (float*)d_out;
  float* ws  = (float*)d_ws;

  k_prep<<<dim3(NBAT + 3), 256, 0, stream>>>(y0, lrc, lic, Bm, Wy2x, by2x, Wx2y, ws);
  k_main<<<dim3(CCH * NBAT), 128, 0, stream>>>(U, bx2y, out, ws);
}

// Round 2
// 295.526 us; speedup vs baseline: 18.8271x; 18.8271x over previous
//
#include <hip/hip_runtime.h>
#include <hip/hip_bf16.h>
#include <stdint.h>

// Problem dims
#define T_HRZ 1024
#define NBAT  128
#define NHID  256
#define NPAIR 128
#define NUIN  64
#define NYOUT 64
#define LCH   16   // chunk length
#define CCH   64   // number of chunks
#define GCH   4    // chunks per group (per block)
#define NGRP  16   // chain length = CCH/GCH

// Workspace layout (float offsets). ~2.3 MB total.
#define WS_LAM   0         // lr[128], li[128]
#define WS_LAML  256       // lambda^16 r[128], i[128]
#define WS_X0P   512       // x0 pair-interleaved [b][j][2] : 128*128*2
#define WS_WBU   33280     // bf16 B-frags for Bu GEMM [nt16][kk2][lane64][j8]
#define WS_WBY   41472     // bf16 B-frags for Y GEMM  [nt4][kk8][lane64][j8]
#define WS_EPUB  49664     // u64 entry-state publications [g][b][j] (524288 floats)
#define WS_FLAG  573952    // u32 flag[g][b] (2048) + ticket u32 at [NGRP*NBAT]

// X16 LDS tile: packed bf16 pairs, pitch 264 shorts (132 dwords, 132%32=4)
#define X16_PITCH 264
// XA LDS tile: padded A-frag layout, b-stride 136 shorts, kk-stride 552
#define XA_SB 136
#define XA_SK 552

typedef __attribute__((ext_vector_type(8))) short short8;
typedef __attribute__((ext_vector_type(4))) float float4v;

union Frag { short8 s8; unsigned int u32[4]; };

__device__ __forceinline__ unsigned int f2bf_bits(float x) {
  unsigned int u = __float_as_uint(x);
  return (u + 0x7fffu + ((u >> 16) & 1u)) >> 16;  // RNE
}

__device__ __forceinline__ unsigned int pkbf(float a, float b) {
  __hip_bfloat162 h = __float22bfloat162_rn(make_float2(a, b));
  union { __hip_bfloat162 h2; unsigned int u; } cv; cv.h2 = h; return cv.u;
}

// ---------------------------------------------------------------------------
// K1: prep. grid (NBAT+3) x 256. Also zeroes chain flags + ticket each launch.
// ---------------------------------------------------------------------------
__global__ __launch_bounds__(256) void k_prep(
    const float* __restrict__ y0, const float* __restrict__ lrc,
    const float* __restrict__ lic, const float* __restrict__ Bm,
    const float* __restrict__ Wy2x, const float* __restrict__ by2x,
    const float* __restrict__ Wx2y, float* __restrict__ ws)
{
  int blk = blockIdx.x;
  int h = threadIdx.x;  // 0..255
  if (blk < NBAT) {
    __shared__ float y0s[NYOUT];
    if (h < NYOUT) y0s[h] = y0[blk * NYOUT + h];
    __syncthreads();
    float acc = by2x[h];
    const float* wr = Wy2x + h * NYOUT;
#pragma unroll 16
    for (int k = 0; k < NYOUT; ++k) acc += y0s[k] * wr[k];
    int j = h & (NPAIR - 1);
    int comp = h >> 7;
    ws[WS_X0P + (blk * NPAIR + j) * 2 + comp] = acc;
  } else if (blk == NBAT) {
    // zero chain flags + ticket counter (must happen before k_main each launch)
    unsigned int* fl = (unsigned int*)(ws + WS_FLAG);
    for (int i = h; i < NGRP * NBAT + 1; i += 256) fl[i] = 0u;
    if (h < NPAIR) {
      float a  = fabsf(lrc[h]);
      float r  = expf(-a);
      float th = 1.5707963267948966f * lic[h];
      float lr = r * cosf(th);
      float li = r * sinf(th);
      ws[WS_LAM + h]         = lr;
      ws[WS_LAM + NPAIR + h] = li;
      float pr = lr, pi_ = li;
      for (int l = 1; l < LCH; ++l) {
        float nr = pr * lr - pi_ * li;
        float ni = pr * li + pi_ * lr;
        pr = nr; pi_ = ni;
      }
      ws[WS_LAML + h]         = pr;  // lambda^16
      ws[WS_LAML + NPAIR + h] = pi_;
    }
  } else if (blk == NBAT + 1) {
    unsigned short* wbu = (unsigned short*)(ws + WS_WBU);
    for (int idx = h; idx < 16384; idx += 256) {
      int nt   = idx >> 10;
      int kk   = (idx >> 9) & 1;
      int lane = (idx >> 3) & 63;
      int jj   = idx & 7;
      int u  = kk * 32 + (lane >> 4) * 8 + jj;
      int hh = nt * 16 + (lane & 15);
      float a2 = fabsf(lrc[hh & (NPAIR - 1)]);
      float nf = sqrtf(1.f - expf(-2.f * a2));
      wbu[idx] = (unsigned short)f2bf_bits(Bm[hh * NUIN + u] * nf);
    }
  } else {
    unsigned short* wby = (unsigned short*)(ws + WS_WBY);
    for (int idx = h; idx < 16384; idx += 256) {
      int nt   = idx >> 12;
      int kk   = (idx >> 9) & 7;
      int lane = (idx >> 3) & 63;
      int jj   = idx & 7;
      int hh = kk * 32 + (lane >> 4) * 8 + jj;
      int y  = nt * 16 + (lane & 15);
      wby[idx] = (unsigned short)f2bf_bits(Wx2y[y * NHID + hh]);
    }
  }
}

// ---------------------------------------------------------------------------
// K2: fused single-pass chained scan. grid NGRP*NBAT x 128 (2 waves).
// Ticket -> (g,b); each block owns GCH=4 consecutive chunks of one batch b.
// Pass 1: per chunk {U load -> Bu MFMA -> LDS transpose -> pk[] to regs},
//         group sum S accumulated in-register across all 64 steps.
// Link:   single-lane RELAXED poll on flag[g-1], one acquire fence, read e.
//         Publish E[g] = Lam^64 * e + S, release flag[g].
// Pass 2: 64-step finish scan from e (pk in regs) -> XA LDS -> Y MFMA -> out.
// U is read ONCE per element; chain is 16 links of 128 parallel b-chains.
// ---------------------------------------------------------------------------
__global__ __launch_bounds__(128, 4) void k_main(
    const float* __restrict__ U, const float* __restrict__ bx2y,
    float* __restrict__ out, float* __restrict__ ws)
{
  // X16 (16*264=4224 shorts) and XA (8*552=4416 shorts) alias SM; every
  // X16 read precedes every XA write across a barrier and vice versa.
  __shared__ unsigned short SM[8 * XA_SK];
  __shared__ unsigned int vid_s;
  int tid = threadIdx.x, wave = tid >> 6, lane = tid & 63;
  int l15 = lane & 15, q = lane >> 4;

  unsigned int* flags = (unsigned int*)(ws + WS_FLAG);
  if (tid == 0) vid_s = atomicAdd(flags + NGRP * NBAT, 1u);  // ticket = start order
  __syncthreads();
  unsigned int vid = vid_s;
  int g = (int)(vid >> 7);        // group (chain dimension), 0..15
  int b = (int)(vid & (NBAT - 1));

  int j = tid;
  float lr = ws[WS_LAM + j],  li = ws[WS_LAM + NPAIR + j];
  float L16r = ws[WS_LAML + j], L16i = ws[WS_LAML + NPAIR + j];
  float L32r = L16r * L16r - L16i * L16i, L32i = 2.f * L16r * L16i;
  float L64r = L32r * L32r - L32i * L32i, L64i = 2.f * L32r * L32i;

  const short8* wbu = (const short8*)(ws + WS_WBU);
  float4v z = {0.f, 0.f, 0.f, 0.f};

  unsigned int pk[GCH][LCH];   // 64 VGPRs: packed bf16 Bu, kept for pass 2
  float S1 = 0.f, S2 = 0.f;    // running group sum (64-step register scan)

  // ---- pass 1: per-chunk Bu MFMA + transpose; accumulate S ----
#pragma unroll
  for (int k = 0; k < GCH; ++k) {
    int c = g * GCH + k;
    const float* urow = U + ((size_t)(c * LCH + l15) * NBAT + b) * NUIN;
    Frag afr[2];
#pragma unroll
    for (int kk = 0; kk < 2; ++kk) {
      int u0 = kk * 32 + q * 8;
      float4 va = *(const float4*)(urow + u0);
      float4 vb = *(const float4*)(urow + u0 + 4);
      afr[kk].u32[0] = pkbf(va.x, va.y);
      afr[kk].u32[1] = pkbf(va.z, va.w);
      afr[kk].u32[2] = pkbf(vb.x, vb.y);
      afr[kk].u32[3] = pkbf(vb.z, vb.w);
    }
    float4v acc[8];
#pragma unroll
    for (int n = 0; n < 8; ++n) acc[n] = z;
#pragma unroll
    for (int n = 0; n < 8; ++n) {
      int nt = wave * 8 + n;
      acc[n] = __builtin_amdgcn_mfma_f32_16x16x32_bf16(afr[0].s8, wbu[(nt * 2 + 0) * 64 + lane], acc[n], 0, 0, 0);
      acc[n] = __builtin_amdgcn_mfma_f32_16x16x32_bf16(afr[1].s8, wbu[(nt * 2 + 1) * 64 + lane], acc[n], 0, 0, 0);
    }
    // C-layout (t=q*4+r, h=(wave*8+n)*16+l15) -> packed pair LDS
#pragma unroll
    for (int n = 0; n < 8; ++n) {
      int hh = (wave * 8 + n) * 16 + l15;
      int off = (hh & 127) * 2 + (hh >> 7);
#pragma unroll
      for (int r = 0; r < 4; ++r)
        SM[(q * 4 + r) * X16_PITCH + off] = (unsigned short)f2bf_bits(acc[n][r]);
    }
    __syncthreads();
#pragma unroll
    for (int l = 0; l < LCH; ++l)
      pk[k][l] = *(const unsigned int*)(SM + l * X16_PITCH + j * 2);
#pragma unroll
    for (int l = 0; l < LCH; ++l) {
      float v1 = __uint_as_float(pk[k][l] << 16);
      float v2 = __uint_as_float(pk[k][l] & 0xffff0000u);
      float n1 = lr * S1 - li * S2 + v1;
      float n2 = li * S1 + lr * S2 + v2;
      S1 = n1; S2 = n2;
    }
    __syncthreads();  // pk reads done before next chunk overwrites X16
  }

  // ---- link: acquire predecessor entry state, publish ours ----
  unsigned long long* epub = (unsigned long long*)(ws + WS_EPUB);
  const size_t cs = (size_t)NBAT * NPAIR;
  size_t o0 = (size_t)b * NPAIR + j;
  float e1, e2;
  if (g == 0) {
    e1 = ws[WS_X0P + (b * NPAIR + j) * 2 + 0];
    e2 = ws[WS_X0P + (b * NPAIR + j) * 2 + 1];
  } else {
    if (tid == 0) {
      unsigned int* fp = flags + (g - 1) * NBAT + b;
      // RELAXED poll: no per-iteration cache-invalidate traffic.
      while (__hip_atomic_load(fp, __ATOMIC_RELAXED, __HIP_MEMORY_SCOPE_AGENT) == 0u)
        __builtin_amdgcn_s_sleep(2);
    }
    __syncthreads();
    // One acquire fence per link (pairs with predecessor's release store).
    __builtin_amdgcn_fence(__ATOMIC_ACQUIRE, "agent");
    unsigned long long pv = __hip_atomic_load(epub + (size_t)(g - 1) * cs + o0,
                                              __ATOMIC_RELAXED, __HIP_MEMORY_SCOPE_AGENT);
    e1 = __uint_as_float((unsigned int)pv);
    e2 = __uint_as_float((unsigned int)(pv >> 32));
  }
  if (g < NGRP - 1) {
    float p1 = L64r * e1 - L64i * e2 + S1;
    float p2 = L64i * e1 + L64r * e2 + S2;
    unsigned long long pv = ((unsigned long long)__float_as_uint(p2) << 32)
                          |  (unsigned long long)__float_as_uint(p1);
    __hip_atomic_store(epub + (size_t)g * cs + o0, pv,
                       __ATOMIC_RELAXED, __HIP_MEMORY_SCOPE_AGENT);
    // Barrier drains all threads' epub stores (vmcnt 0 before s_barrier),
    // then tid0's release makes them agent-visible before the flag flips.
    __syncthreads();
    if (tid == 0)
      __hip_atomic_store(flags + g * NBAT + b, 1u,
                         __ATOMIC_RELEASE, __HIP_MEMORY_SCOPE_AGENT);
  }

  // ---- pass 2: finish scan from e; per chunk write XA, Y-MFMA, store ----
  const short8* wby = (const short8*)(ws + WS_WBY);
  int base1 = (j >> 5) * XA_SK       + ((j >> 3) & 3) * XA_SB + (j & 7);
  int base2 = ((j >> 5) + 4) * XA_SK + ((j >> 3) & 3) * XA_SB + (j & 7);
  float x1 = e1, x2 = e2;
  float bias0 = bx2y[(wave * 2 + 0) * 16 + l15];
  float bias1 = bx2y[(wave * 2 + 1) * 16 + l15];
#pragma unroll
  for (int k = 0; k < GCH; ++k) {
    int c = g * GCH + k;
#pragma unroll
    for (int l = 0; l < LCH; ++l) {
      float v1 = __uint_as_float(pk[k][l] << 16);
      float v2 = __uint_as_float(pk[k][l] & 0xffff0000u);
      float n1 = lr * x1 - li * x2 + v1;
      float n2 = li * x1 + lr * x2 + v2;
      x1 = n1; x2 = n2;
      SM[base1 + l * 8] = (unsigned short)f2bf_bits(x1);
      SM[base2 + l * 8] = (unsigned short)f2bf_bits(x2);
    }
    __syncthreads();
    float4v acc0 = z, acc1 = z;
    int nt0 = wave * 2, nt1 = nt0 + 1;
#pragma unroll
    for (int kk = 0; kk < 8; ++kk) {
      short8 a = *(const short8*)(SM + kk * XA_SK + q * XA_SB + l15 * 8);
      acc0 = __builtin_amdgcn_mfma_f32_16x16x32_bf16(a, wby[(nt0 * 8 + kk) * 64 + lane], acc0, 0, 0, 0);
      acc1 = __builtin_amdgcn_mfma_f32_16x16x32_bf16(a, wby[(nt1 * 8 + kk) * 64 + lane], acc1, 0, 0, 0);
    }
#pragma unroll
    for (int r = 0; r < 4; ++r) {
      int row = q * 4 + r;  // t within chunk
      size_t o = ((size_t)(c * LCH + row) * NBAT + b) * NYOUT;
      out[o + nt0 * 16 + l15] = acc0[r] + bias0;
      out[o + nt1 * 16 + l15] = acc1[r] + bias1;
    }
    if (k < GCH - 1) __syncthreads();  // XA reads done before next overwrite
  }
}

// ---------------------------------------------------------------------------
extern "C" void kernel_launch(void* const* d_in, const int* in_sizes, int n_in,
                              void* d_out, int out_size, void* d_ws, size_t ws_size,
                              hipStream_t stream) {
  (void)in_sizes; (void)n_in; (void)out_size; (void)ws_size;
  const float* y0   = (const float*)d_in[0];
  const float* U    = (const float*)d_in[1];
  const float* lrc  = (const float*)d_in[2];
  const float* lic  = (const float*)d_in[3];
  const float* Bm   = (const float*)d_in[4];
  const float* Wy2x = (const float*)d_in[5];
  const float* by2x = (const float*)d_in[6];
  const float* Wx2y = (const float*)d_in[7];
  const float* bx2y = (const float*)d_in[8];
  float* out = (float*)d_out;
  float* ws  = (float*)d_ws;

  k_prep<<<dim3(NBAT + 3), 256, 0, stream>>>(y0, lrc, lic, Bm, Wy2x, by2x, Wx2y, ws);
  k_main<<<dim3(NGRP * NBAT), 128, 0, stream>>>(U, bx2y, out, ws);
}

// Round 3
// 201.313 us; speedup vs baseline: 27.6380x; 1.4680x over previous
//
#include <hip/hip_runtime.h>
#include <hip/hip_bf16.h>
#include <stdint.h>

// Problem dims
#define T_HRZ 1024
#define NBAT  128
#define NHID  256
#define NPAIR 128
#define NUIN  64
#define NYOUT 64
#define LCH   16   // chunk length
#define CCH   64   // number of chunks
#define GCH   4    // chunks per group (per block)
#define NGRP  16   // groups per batch chain = CCH/GCH

// Workspace layout (float offsets). ~2.3 MB total.
#define WS_LAM   0         // lr[128], li[128]
#define WS_LAML  256       // lambda^16 r[128], i[128]
#define WS_X0P   512       // x0 pair-interleaved [b][j][2] : 128*128*2
#define WS_WBU   33280     // bf16 B-frags for Bu GEMM [nt16][kk2][lane64][j8]
#define WS_WBY   41472     // bf16 B-frags for Y GEMM  [nt4][kk8][lane64][j8]
#define WS_SPUB  49664     // u64 group-sum publications [g][b][j] (524288 floats)
#define WS_CNT   573952    // u32 mask[b] at b*16 (stride 64B) + ticket at [2048]

// X16 LDS tile: packed bf16 pairs, pitch 264 shorts (132 dwords, 132%32=4)
#define X16_PITCH 264
// XA LDS tile: padded A-frag layout, b-stride 136 shorts, kk-stride 552
#define XA_SB 136
#define XA_SK 552

typedef __attribute__((ext_vector_type(8))) short short8;
typedef __attribute__((ext_vector_type(4))) float float4v;

union Frag { short8 s8; unsigned int u32[4]; };

__device__ __forceinline__ unsigned int f2bf_bits(float x) {
  unsigned int u = __float_as_uint(x);
  return (u + 0x7fffu + ((u >> 16) & 1u)) >> 16;  // RNE
}

__device__ __forceinline__ unsigned int pkbf(float a, float b) {
  __hip_bfloat162 h = __float22bfloat162_rn(make_float2(a, b));
  union { __hip_bfloat162 h2; unsigned int u; } cv; cv.h2 = h; return cv.u;
}

// ---------------------------------------------------------------------------
// K1: prep. grid (NBAT+3) x 256. Also zeroes join masks + ticket each launch.
// ---------------------------------------------------------------------------
__global__ __launch_bounds__(256) void k_prep(
    const float* __restrict__ y0, const float* __restrict__ lrc,
    const float* __restrict__ lic, const float* __restrict__ Bm,
    const float* __restrict__ Wy2x, const float* __restrict__ by2x,
    const float* __restrict__ Wx2y, float* __restrict__ ws)
{
  int blk = blockIdx.x;
  int h = threadIdx.x;  // 0..255
  if (blk < NBAT) {
    __shared__ float y0s[NYOUT];
    if (h < NYOUT) y0s[h] = y0[blk * NYOUT + h];
    __syncthreads();
    float acc = by2x[h];
    const float* wr = Wy2x + h * NYOUT;
#pragma unroll 16
    for (int k = 0; k < NYOUT; ++k) acc += y0s[k] * wr[k];
    int j = h & (NPAIR - 1);
    int comp = h >> 7;
    ws[WS_X0P + (blk * NPAIR + j) * 2 + comp] = acc;
  } else if (blk == NBAT) {
    // zero join masks + ticket (must happen before k_main each launch)
    unsigned int* fl = (unsigned int*)(ws + WS_CNT);
    for (int i = h; i < NBAT * 16 + 1; i += 256) fl[i] = 0u;
    if (h < NPAIR) {
      float a  = fabsf(lrc[h]);
      float r  = expf(-a);
      float th = 1.5707963267948966f * lic[h];
      float lr = r * cosf(th);
      float li = r * sinf(th);
      ws[WS_LAM + h]         = lr;
      ws[WS_LAM + NPAIR + h] = li;
      float pr = lr, pi_ = li;
      for (int l = 1; l < LCH; ++l) {
        float nr = pr * lr - pi_ * li;
        float ni = pr * li + pi_ * lr;
        pr = nr; pi_ = ni;
      }
      ws[WS_LAML + h]         = pr;  // lambda^16
      ws[WS_LAML + NPAIR + h] = pi_;
    }
  } else if (blk == NBAT + 1) {
    unsigned short* wbu = (unsigned short*)(ws + WS_WBU);
    for (int idx = h; idx < 16384; idx += 256) {
      int nt   = idx >> 10;
      int kk   = (idx >> 9) & 1;
      int lane = (idx >> 3) & 63;
      int jj   = idx & 7;
      int u  = kk * 32 + (lane >> 4) * 8 + jj;
      int hh = nt * 16 + (lane & 15);
      float a2 = fabsf(lrc[hh & (NPAIR - 1)]);
      float nf = sqrtf(1.f - expf(-2.f * a2));
      wbu[idx] = (unsigned short)f2bf_bits(Bm[hh * NUIN + u] * nf);
    }
  } else {
    unsigned short* wby = (unsigned short*)(ws + WS_WBY);
    for (int idx = h; idx < 16384; idx += 256) {
      int nt   = idx >> 12;
      int kk   = (idx >> 9) & 7;
      int lane = (idx >> 3) & 63;
      int jj   = idx & 7;
      int hh = kk * 32 + (lane >> 4) * 8 + jj;
      int y  = nt * 16 + (lane & 15);
      wby[idx] = (unsigned short)f2bf_bits(Wx2y[y * NHID + hh]);
    }
  }
}

// ---------------------------------------------------------------------------
// K2: fused single-pass scan with parallel lookback JOIN (no serial chain).
// grid NGRP*NBAT x 128 (2 waves). Ticket -> (g,b); block owns GCH=4 chunks.
// Pass 1: per chunk {U load -> Bu MFMA -> LDS transpose -> pk[] to regs},
//         group sum S accumulated in-register across 64 steps.
// Publish: S via relaxed agent atomics; __syncthreads drains vmcnt; tid0
//          atomicOr's bit g into mask[b]. NO cache fences anywhere.
// Join:    tid0 polls mask[b] (relaxed) until bits 0..g-1 set; prefetch all
//          predecessor S values; Horner e = L64*e + S[g'] (op-for-op
//          identical to the old chain => bitwise-identical results).
// Pass 2: 64-step finish scan from e (pk in regs) -> XA LDS -> Y MFMA -> out.
// Deadlock-free: ticket order => waits only ever target lower tickets.
// ---------------------------------------------------------------------------
__global__ __launch_bounds__(128, 4) void k_main(
    const float* __restrict__ U, const float* __restrict__ bx2y,
    float* __restrict__ out, float* __restrict__ ws)
{
  // X16 (16*264=4224 shorts) and XA (8*552=4416 shorts) alias SM; every
  // X16 read precedes every XA write across a barrier and vice versa.
  __shared__ unsigned short SM[8 * XA_SK];
  __shared__ unsigned int vid_s;
  int tid = threadIdx.x, wave = tid >> 6, lane = tid & 63;
  int l15 = lane & 15, q = lane >> 4;

  unsigned int* cnt = (unsigned int*)(ws + WS_CNT);
  if (tid == 0) vid_s = atomicAdd(cnt + NBAT * 16, 1u);  // ticket = start order
  __syncthreads();
  unsigned int vid = vid_s;
  int g = (int)(vid >> 7);        // group, 0..15
  int b = (int)(vid & (NBAT - 1));

  int j = tid;
  float lr = ws[WS_LAM + j],  li = ws[WS_LAM + NPAIR + j];
  float L16r = ws[WS_LAML + j], L16i = ws[WS_LAML + NPAIR + j];
  float L32r = L16r * L16r - L16i * L16i, L32i = 2.f * L16r * L16i;
  float L64r = L32r * L32r - L32i * L32i, L64i = 2.f * L32r * L32i;

  const short8* wbu = (const short8*)(ws + WS_WBU);
  float4v z = {0.f, 0.f, 0.f, 0.f};

  unsigned int pk[GCH][LCH];   // 64 VGPRs: packed bf16 Bu, kept for pass 2
  float S1 = 0.f, S2 = 0.f;    // running group sum (64-step register scan)

  // ---- pass 1: per-chunk Bu MFMA + transpose; accumulate S ----
#pragma unroll
  for (int k = 0; k < GCH; ++k) {
    int c = g * GCH + k;
    const float* urow = U + ((size_t)(c * LCH + l15) * NBAT + b) * NUIN;
    Frag afr[2];
#pragma unroll
    for (int kk = 0; kk < 2; ++kk) {
      int u0 = kk * 32 + q * 8;
      float4 va = *(const float4*)(urow + u0);
      float4 vb = *(const float4*)(urow + u0 + 4);
      afr[kk].u32[0] = pkbf(va.x, va.y);
      afr[kk].u32[1] = pkbf(va.z, va.w);
      afr[kk].u32[2] = pkbf(vb.x, vb.y);
      afr[kk].u32[3] = pkbf(vb.z, vb.w);
    }
    float4v acc[8];
#pragma unroll
    for (int n = 0; n < 8; ++n) acc[n] = z;
#pragma unroll
    for (int n = 0; n < 8; ++n) {
      int nt = wave * 8 + n;
      acc[n] = __builtin_amdgcn_mfma_f32_16x16x32_bf16(afr[0].s8, wbu[(nt * 2 + 0) * 64 + lane], acc[n], 0, 0, 0);
      acc[n] = __builtin_amdgcn_mfma_f32_16x16x32_bf16(afr[1].s8, wbu[(nt * 2 + 1) * 64 + lane], acc[n], 0, 0, 0);
    }
    // C-layout (t=q*4+r, h=(wave*8+n)*16+l15) -> packed pair LDS
#pragma unroll
    for (int n = 0; n < 8; ++n) {
      int hh = (wave * 8 + n) * 16 + l15;
      int off = (hh & 127) * 2 + (hh >> 7);
#pragma unroll
      for (int r = 0; r < 4; ++r)
        SM[(q * 4 + r) * X16_PITCH + off] = (unsigned short)f2bf_bits(acc[n][r]);
    }
    __syncthreads();
#pragma unroll
    for (int l = 0; l < LCH; ++l)
      pk[k][l] = *(const unsigned int*)(SM + l * X16_PITCH + j * 2);
#pragma unroll
    for (int l = 0; l < LCH; ++l) {
      float v1 = __uint_as_float(pk[k][l] << 16);
      float v2 = __uint_as_float(pk[k][l] & 0xffff0000u);
      float n1 = lr * S1 - li * S2 + v1;
      float n2 = li * S1 + lr * S2 + v2;
      S1 = n1; S2 = n2;
    }
    __syncthreads();  // pk reads done before next chunk overwrites X16
  }

  // ---- publish S (independent of predecessors => no serial chain) ----
  unsigned long long* spub = (unsigned long long*)(ws + WS_SPUB);
  const size_t cs = (size_t)NBAT * NPAIR;
  size_t o0 = (size_t)b * NPAIR + j;
  if (g < NGRP - 1) {
    unsigned long long pv = ((unsigned long long)__float_as_uint(S2) << 32)
                          |  (unsigned long long)__float_as_uint(S1);
    __hip_atomic_store(spub + (size_t)g * cs + o0, pv,
                       __ATOMIC_RELAXED, __HIP_MEMORY_SCOPE_AGENT);
  }
  // Barrier waits each thread's vmcnt(0): all S atomics are at the coherence
  // point before tid0 flips the mask bit. No wbl2/inv needed (all atomics).
  __syncthreads();
  if (tid == 0 && g < NGRP - 1)
    atomicOr(cnt + b * 16, 1u << g);

  // ---- join: wait for ALL predecessors' S bits, then local Horner ----
  float e1, e2;
  e1 = ws[WS_X0P + (b * NPAIR + j) * 2 + 0];
  e2 = ws[WS_X0P + (b * NPAIR + j) * 2 + 1];
  if (g > 0) {
    unsigned int need = (1u << g) - 1u;
    if (tid == 0) {
      while ((__hip_atomic_load(cnt + b * 16, __ATOMIC_RELAXED,
                                __HIP_MEMORY_SCOPE_AGENT) & need) != need)
        __builtin_amdgcn_s_sleep(1);
    }
    __syncthreads();
    unsigned long long sv[NGRP - 1];
#pragma unroll
    for (int g2 = 0; g2 < NGRP - 1; ++g2)
      if (g2 < g)
        sv[g2] = __hip_atomic_load(spub + (size_t)g2 * cs + o0,
                                   __ATOMIC_RELAXED, __HIP_MEMORY_SCOPE_AGENT);
#pragma unroll
    for (int g2 = 0; g2 < NGRP - 1; ++g2)
      if (g2 < g) {
        float s1 = __uint_as_float((unsigned int)sv[g2]);
        float s2 = __uint_as_float((unsigned int)(sv[g2] >> 32));
        float n1 = L64r * e1 - L64i * e2 + s1;
        float n2 = L64i * e1 + L64r * e2 + s2;
        e1 = n1; e2 = n2;
      }
  }

  // ---- pass 2: finish scan from e; per chunk write XA, Y-MFMA, store ----
  const short8* wby = (const short8*)(ws + WS_WBY);
  int base1 = (j >> 5) * XA_SK       + ((j >> 3) & 3) * XA_SB + (j & 7);
  int base2 = ((j >> 5) + 4) * XA_SK + ((j >> 3) & 3) * XA_SB + (j & 7);
  float x1 = e1, x2 = e2;
  float bias0 = bx2y[(wave * 2 + 0) * 16 + l15];
  float bias1 = bx2y[(wave * 2 + 1) * 16 + l15];
#pragma unroll
  for (int k = 0; k < GCH; ++k) {
    int c = g * GCH + k;
#pragma unroll
    for (int l = 0; l < LCH; ++l) {
      float v1 = __uint_as_float(pk[k][l] << 16);
      float v2 = __uint_as_float(pk[k][l] & 0xffff0000u);
      float n1 = lr * x1 - li * x2 + v1;
      float n2 = li * x1 + lr * x2 + v2;
      x1 = n1; x2 = n2;
      SM[base1 + l * 8] = (unsigned short)f2bf_bits(x1);
      SM[base2 + l * 8] = (unsigned short)f2bf_bits(x2);
    }
    __syncthreads();
    float4v acc0 = z, acc1 = z;
    int nt0 = wave * 2, nt1 = nt0 + 1;
#pragma unroll
    for (int kk = 0; kk < 8; ++kk) {
      short8 a = *(const short8*)(SM + kk * XA_SK + q * XA_SB + l15 * 8);
      acc0 = __builtin_amdgcn_mfma_f32_16x16x32_bf16(a, wby[(nt0 * 8 + kk) * 64 + lane], acc0, 0, 0, 0);
      acc1 = __builtin_amdgcn_mfma_f32_16x16x32_bf16(a, wby[(nt1 * 8 + kk) * 64 + lane], acc1, 0, 0, 0);
    }
#pragma unroll
    for (int r = 0; r < 4; ++r) {
      int row = q * 4 + r;  // t within chunk
      size_t o = ((size_t)(c * LCH + row) * NBAT + b) * NYOUT;
      out[o + nt0 * 16 + l15] = acc0[r] + bias0;
      out[o + nt1 * 16 + l15] = acc1[r] + bias1;
    }
    if (k < GCH - 1) __syncthreads();  // XA reads done before next overwrite
  }
}

// ---------------------------------------------------------------------------
extern "C" void kernel_launch(void* const* d_in, const int* in_sizes, int n_in,
                              void* d_out, int out_size, void* d_ws, size_t ws_size,
                              hipStream_t stream) {
  (void)in_sizes; (void)n_in; (void)out_size; (void)ws_size;
  const float* y0   = (const float*)d_in[0];
  const float* U    = (const float*)d_in[1];
  const float* lrc  = (const float*)d_in[2];
  const float* lic  = (const float*)d_in[3];
  const float* Bm   = (const float*)d_in[4];
  const float* Wy2x = (const float*)d_in[5];
  const float* by2x = (const float*)d_in[6];
  const float* Wx2y = (const float*)d_in[7];
  const float* bx2y = (const float*)d_in[8];
  float* out = (float*)d_out;
  float* ws  = (float*)d_ws;

  k_prep<<<dim3(NBAT + 3), 256, 0, stream>>>(y0, lrc, lic, Bm, Wy2x, by2x, Wx2y, ws);
  k_main<<<dim3(NGRP * NBAT), 128, 0, stream>>>(U, bx2y, out, ws);
}

// Round 5
// 181.052 us; speedup vs baseline: 30.7308x; 1.1119x over previous
//
#include <hip/hip_runtime.h>
#include <hip/hip_bf16.h>
#include <stdint.h>

// Problem dims
#define T_HRZ 1024
#define NBAT  128
#define NHID  256
#define NPAIR 128
#define NUIN  64
#define NYOUT 64
#define LCH   16   // chunk length
#define CCH   64   // number of chunks
#define GCH   4    // chunks per group (per block)
#define NGRP  16   // groups per batch chain = CCH/GCH

// Workspace layout (float offsets). ~2.3 MB total.
#define WS_LAM   0         // lr[128], li[128]
#define WS_LAML  256       // lambda^16 r[128], i[128]
#define WS_X0P   512       // x0 pair-interleaved [b][j][2] : 128*128*2
#define WS_WBU   33280     // bf16 B-frags for Bu GEMM [nt16][kk2][lane64][j8]
#define WS_WBY   41472     // bf16 B-frags for Y GEMM  [nt4][kk8][lane64][j8]
#define WS_SPUB  49664     // u64 group-sum publications [g][b][j] (524288 floats)
#define WS_CNT   573952    // u32 mask[b] at b*16 (stride 64B) + ticket at [2048]

// X16 LDS tile: packed bf16 pairs, pitch 264 shorts (132 dwords, 132%32=4)
#define X16_PITCH 264
// XA LDS tile: padded A-frag layout, b-stride 136 shorts, kk-stride 552
#define XA_SB 136
#define XA_SK 552

typedef __attribute__((ext_vector_type(8))) short short8;
typedef __attribute__((ext_vector_type(4))) float float4v;

union Frag { short8 s8; unsigned int u32[4]; };

__device__ __forceinline__ unsigned int f2bf_bits(float x) {
  unsigned int u = __float_as_uint(x);
  return (u + 0x7fffu + ((u >> 16) & 1u)) >> 16;  // RNE
}

__device__ __forceinline__ unsigned int pkbf(float a, float b) {
  __hip_bfloat162 h = __float22bfloat162_rn(make_float2(a, b));
  union { __hip_bfloat162 h2; unsigned int u; } cv; cv.h2 = h; return cv.u;
}

// ---------------------------------------------------------------------------
// K1: prep. grid (NBAT+3) x 256. Also zeroes join masks + ticket each launch.
// ---------------------------------------------------------------------------
__global__ __launch_bounds__(256) void k_prep(
    const float* __restrict__ y0, const float* __restrict__ lrc,
    const float* __restrict__ lic, const float* __restrict__ Bm,
    const float* __restrict__ Wy2x, const float* __restrict__ by2x,
    const float* __restrict__ Wx2y, float* __restrict__ ws)
{
  int blk = blockIdx.x;
  int h = threadIdx.x;  // 0..255
  if (blk < NBAT) {
    __shared__ float y0s[NYOUT];
    if (h < NYOUT) y0s[h] = y0[blk * NYOUT + h];
    __syncthreads();
    float acc = by2x[h];
    const float* wr = Wy2x + h * NYOUT;
#pragma unroll 16
    for (int k = 0; k < NYOUT; ++k) acc += y0s[k] * wr[k];
    int j = h & (NPAIR - 1);
    int comp = h >> 7;
    ws[WS_X0P + (blk * NPAIR + j) * 2 + comp] = acc;
  } else if (blk == NBAT) {
    // zero join masks + ticket (must happen before k_main each launch)
    unsigned int* fl = (unsigned int*)(ws + WS_CNT);
    for (int i = h; i < NBAT * 16 + 1; i += 256) fl[i] = 0u;
    if (h < NPAIR) {
      float a  = fabsf(lrc[h]);
      float r  = expf(-a);
      float th = 1.5707963267948966f * lic[h];
      float lr = r * cosf(th);
      float li = r * sinf(th);
      ws[WS_LAM + h]         = lr;
      ws[WS_LAM + NPAIR + h] = li;
      float pr = lr, pi_ = li;
      for (int l = 1; l < LCH; ++l) {
        float nr = pr * lr - pi_ * li;
        float ni = pr * li + pi_ * lr;
        pr = nr; pi_ = ni;
      }
      ws[WS_LAML + h]         = pr;  // lambda^16
      ws[WS_LAML + NPAIR + h] = pi_;
    }
  } else if (blk == NBAT + 1) {
    unsigned short* wbu = (unsigned short*)(ws + WS_WBU);
    for (int idx = h; idx < 16384; idx += 256) {
      int nt   = idx >> 10;
      int kk   = (idx >> 9) & 1;
      int lane = (idx >> 3) & 63;
      int jj   = idx & 7;
      int u  = kk * 32 + (lane >> 4) * 8 + jj;
      int hh = nt * 16 + (lane & 15);
      float a2 = fabsf(lrc[hh & (NPAIR - 1)]);
      float nf = sqrtf(1.f - expf(-2.f * a2));
      wbu[idx] = (unsigned short)f2bf_bits(Bm[hh * NUIN + u] * nf);
    }
  } else {
    unsigned short* wby = (unsigned short*)(ws + WS_WBY);
    for (int idx = h; idx < 16384; idx += 256) {
      int nt   = idx >> 12;
      int kk   = (idx >> 9) & 7;
      int lane = (idx >> 3) & 63;
      int jj   = idx & 7;
      int hh = kk * 32 + (lane >> 4) * 8 + jj;
      int y  = nt * 16 + (lane & 15);
      wby[idx] = (unsigned short)f2bf_bits(Wx2y[y * NHID + hh]);
    }
  }
}

// ---------------------------------------------------------------------------
// K2: fused single-pass scan with parallel lookback JOIN (no serial chain).
// grid NGRP*NBAT x 128 (2 waves). Ticket -> (g,b); block owns GCH=4 chunks.
// Pass 1: per chunk {U load -> Bu MFMA -> LDS transpose -> pk[] to regs},
//         group sum S accumulated in-register across 64 steps.
// Publish: S via relaxed agent atomics; __syncthreads drains vmcnt; tid0
//          atomicOr's bit g into mask[b]. NO cache fences anywhere.
// Join:    tid0 polls mask[b] (relaxed) until bits 0..g-1 set; prefetch all
//          predecessor S values; Horner e = L64*e + S[g'].
// Pass 2: 64-step finish scan from e (pk in regs) -> XA LDS -> Y MFMA -> out.
// Deadlock-free: ticket order => waits only ever target lower tickets.
//
// __launch_bounds__(128, 3): VGPR cap 512/3 = 170. pk[4][16] (64 VGPRs) +
// acc (32) + live scalars ~= 125-150 must STAY IN REGISTERS. At min_waves=4
// (cap 128) the allocator wholesale-spilled pk -> 64 MB of scratch writes
// per dispatch (round-3 WRITE_SIZE=100MB, VGPR=64). 6 blocks/CU is plenty.
// ---------------------------------------------------------------------------
__global__ __launch_bounds__(128, 3) void k_main(
    const float* __restrict__ U, const float* __restrict__ bx2y,
    float* __restrict__ out, float* __restrict__ ws)
{
  // X16 (16*264=4224 shorts) and XA (8*552=4416 shorts) alias SM; every
  // X16 read precedes every XA write across a barrier and vice versa.
  __shared__ unsigned short SM[8 * XA_SK];
  __shared__ unsigned int vid_s;
  int tid = threadIdx.x, wave = tid >> 6, lane = tid & 63;
  int l15 = lane & 15, q = lane >> 4;

  unsigned int* cnt = (unsigned int*)(ws + WS_CNT);
  if (tid == 0) vid_s = atomicAdd(cnt + NBAT * 16, 1u);  // ticket = start order
  __syncthreads();
  unsigned int vid = vid_s;
  int g = (int)(vid >> 7);        // group, 0..15
  int b = (int)(vid & (NBAT - 1));

  int j = tid;
  float lr = ws[WS_LAM + j],  li = ws[WS_LAM + NPAIR + j];
  float L16r = ws[WS_LAML + j], L16i = ws[WS_LAML + NPAIR + j];
  float L32r = L16r * L16r - L16i * L16i, L32i = 2.f * L16r * L16i;
  float L64r = L32r * L32r - L32i * L32i, L64i = 2.f * L32r * L32i;

  const short8* wbu = (const short8*)(ws + WS_WBU);
  float4v z = {0.f, 0.f, 0.f, 0.f};

  unsigned int pk[GCH][LCH];   // 64 VGPRs: packed bf16 Bu, kept for pass 2
  float S1 = 0.f, S2 = 0.f;    // running group sum (64-step register scan)

  // ---- pass 1: per-chunk Bu MFMA + transpose; accumulate S ----
#pragma unroll
  for (int k = 0; k < GCH; ++k) {
    int c = g * GCH + k;
    const float* urow = U + ((size_t)(c * LCH + l15) * NBAT + b) * NUIN;
    Frag afr[2];
#pragma unroll
    for (int kk = 0; kk < 2; ++kk) {
      int u0 = kk * 32 + q * 8;
      float4 va = *(const float4*)(urow + u0);
      float4 vb = *(const float4*)(urow + u0 + 4);
      afr[kk].u32[0] = pkbf(va.x, va.y);
      afr[kk].u32[1] = pkbf(va.z, va.w);
      afr[kk].u32[2] = pkbf(vb.x, vb.y);
      afr[kk].u32[3] = pkbf(vb.z, vb.w);
    }
    float4v acc[8];
#pragma unroll
    for (int n = 0; n < 8; ++n) acc[n] = z;
#pragma unroll
    for (int n = 0; n < 8; ++n) {
      int nt = wave * 8 + n;
      acc[n] = __builtin_amdgcn_mfma_f32_16x16x32_bf16(afr[0].s8, wbu[(nt * 2 + 0) * 64 + lane], acc[n], 0, 0, 0);
      acc[n] = __builtin_amdgcn_mfma_f32_16x16x32_bf16(afr[1].s8, wbu[(nt * 2 + 1) * 64 + lane], acc[n], 0, 0, 0);
    }
    // C-layout (t=q*4+r, h=(wave*8+n)*16+l15) -> packed pair LDS
#pragma unroll
    for (int n = 0; n < 8; ++n) {
      int hh = (wave * 8 + n) * 16 + l15;
      int off = (hh & 127) * 2 + (hh >> 7);
#pragma unroll
      for (int r = 0; r < 4; ++r)
        SM[(q * 4 + r) * X16_PITCH + off] = (unsigned short)f2bf_bits(acc[n][r]);
    }
    __syncthreads();
#pragma unroll
    for (int l = 0; l < LCH; ++l)
      pk[k][l] = *(const unsigned int*)(SM + l * X16_PITCH + j * 2);
#pragma unroll
    for (int l = 0; l < LCH; ++l) {
      float v1 = __uint_as_float(pk[k][l] << 16);
      float v2 = __uint_as_float(pk[k][l] & 0xffff0000u);
      float n1 = lr * S1 - li * S2 + v1;
      float n2 = li * S1 + lr * S2 + v2;
      S1 = n1; S2 = n2;
    }
    __syncthreads();  // pk reads done before next chunk overwrites X16
  }

  // ---- publish S (independent of predecessors => no serial chain) ----
  unsigned long long* spub = (unsigned long long*)(ws + WS_SPUB);
  const size_t cs = (size_t)NBAT * NPAIR;
  size_t o0 = (size_t)b * NPAIR + j;
  if (g < NGRP - 1) {
    unsigned long long pv = ((unsigned long long)__float_as_uint(S2) << 32)
                          |  (unsigned long long)__float_as_uint(S1);
    __hip_atomic_store(spub + (size_t)g * cs + o0, pv,
                       __ATOMIC_RELAXED, __HIP_MEMORY_SCOPE_AGENT);
  }
  // Barrier waits each thread's vmcnt(0): all S atomics are at the coherence
  // point before tid0 flips the mask bit. No wbl2/inv needed (all atomics).
  __syncthreads();
  if (tid == 0 && g < NGRP - 1)
    atomicOr(cnt + b * 16, 1u << g);

  // ---- join: wait for ALL predecessors' S bits, then local Horner ----
  float e1, e2;
  e1 = ws[WS_X0P + (b * NPAIR + j) * 2 + 0];
  e2 = ws[WS_X0P + (b * NPAIR + j) * 2 + 1];
  if (g > 0) {
    unsigned int need = (1u << g) - 1u;
    if (tid == 0) {
      while ((__hip_atomic_load(cnt + b * 16, __ATOMIC_RELAXED,
                                __HIP_MEMORY_SCOPE_AGENT) & need) != need)
        __builtin_amdgcn_s_sleep(1);
    }
    __syncthreads();
    unsigned long long sv[NGRP - 1];
#pragma unroll
    for (int g2 = 0; g2 < NGRP - 1; ++g2)
      if (g2 < g)
        sv[g2] = __hip_atomic_load(spub + (size_t)g2 * cs + o0,
                                   __ATOMIC_RELAXED, __HIP_MEMORY_SCOPE_AGENT);
#pragma unroll
    for (int g2 = 0; g2 < NGRP - 1; ++g2)
      if (g2 < g) {
        float s1 = __uint_as_float((unsigned int)sv[g2]);
        float s2 = __uint_as_float((unsigned int)(sv[g2] >> 32));
        float n1 = L64r * e1 - L64i * e2 + s1;
        float n2 = L64i * e1 + L64r * e2 + s2;
        e1 = n1; e2 = n2;
      }
  }

  // ---- pass 2: finish scan from e; per chunk write XA, Y-MFMA, store ----
  const short8* wby = (const short8*)(ws + WS_WBY);
  int base1 = (j >> 5) * XA_SK       + ((j >> 3) & 3) * XA_SB + (j & 7);
  int base2 = ((j >> 5) + 4) * XA_SK + ((j >> 3) & 3) * XA_SB + (j & 7);
  float x1 = e1, x2 = e2;
  float bias0 = bx2y[(wave * 2 + 0) * 16 + l15];
  float bias1 = bx2y[(wave * 2 + 1) * 16 + l15];
#pragma unroll
  for (int k = 0; k < GCH; ++k) {
    int c = g * GCH + k;
#pragma unroll
    for (int l = 0; l < LCH; ++l) {
      float v1 = __uint_as_float(pk[k][l] << 16);
      float v2 = __uint_as_float(pk[k][l] & 0xffff0000u);
      float n1 = lr * x1 - li * x2 + v1;
      float n2 = li * x1 + lr * x2 + v2;
      x1 = n1; x2 = n2;
      SM[base1 + l * 8] = (unsigned short)f2bf_bits(x1);
      SM[base2 + l * 8] = (unsigned short)f2bf_bits(x2);
    }
    __syncthreads();
    float4v acc0 = z, acc1 = z;
    int nt0 = wave * 2, nt1 = nt0 + 1;
#pragma unroll
    for (int kk = 0; kk < 8; ++kk) {
      short8 a = *(const short8*)(SM + kk * XA_SK + q * XA_SB + l15 * 8);
      acc0 = __builtin_amdgcn_mfma_f32_16x16x32_bf16(a, wby[(nt0 * 8 + kk) * 64 + lane], acc0, 0, 0, 0);
      acc1 = __builtin_amdgcn_mfma_f32_16x16x32_bf16(a, wby[(nt1 * 8 + kk) * 64 + lane], acc1, 0, 0, 0);
    }
#pragma unroll
    for (int r = 0; r < 4; ++r) {
      int row = q * 4 + r;  // t within chunk
      size_t o = ((size_t)(c * LCH + row) * NBAT + b) * NYOUT;
      out[o + nt0 * 16 + l15] = acc0[r] + bias0;
      out[o + nt1 * 16 + l15] = acc1[r] + bias1;
    }
    if (k < GCH - 1) __syncthreads();  // XA reads done before next overwrite
  }
}

// ---------------------------------------------------------------------------
extern "C" void kernel_launch(void* const* d_in, const int* in_sizes, int n_in,
                              void* d_out, int out_size, void* d_ws, size_t ws_size,
                              hipStream_t stream) {
  (void)in_sizes; (void)n_in; (void)out_size; (void)ws_size;
  const float* y0   = (const float*)d_in[0];
  const float* U    = (const float*)d_in[1];
  const float* lrc  = (const float*)d_in[2];
  const float* lic  = (const float*)d_in[3];
  const float* Bm   = (const float*)d_in[4];
  const float* Wy2x = (const float*)d_in[5];
  const float* by2x = (const float*)d_in[6];
  const float* Wx2y = (const float*)d_in[7];
  const float* bx2y = (const float*)d_in[8];
  float* out = (float*)d_out;
  float* ws  = (float*)d_ws;

  k_prep<<<dim3(NBAT + 3), 256, 0, stream>>>(y0, lrc, lic, Bm, Wy2x, by2x, Wx2y, ws);
  k_main<<<dim3(NGRP * NBAT), 128, 0, stream>>>(U, bx2y, out, ws);
}